// Round 4
// baseline (621.067 us; speedup 1.0000x reference)
//
#include <hip/hip_runtime.h>

typedef unsigned short u16;
typedef unsigned int u32;
typedef __bf16 bf16x8 __attribute__((ext_vector_type(8)));
typedef float floatx4 __attribute__((ext_vector_type(4)));

#define HID 1024
#define BATCH 64
#define SEQ 256
#define INDIM 128
#define OUTDIM 128
#define MROWS (BATCH*SEQ)   // 16384

__device__ __forceinline__ float b2f(u16 u) {
    union { u32 u; float f; } v; v.u = ((u32)u) << 16; return v.f;
}
__device__ __forceinline__ u16 f2b(float f) {
    union { float f; u32 u; } v; v.f = f;
    u32 x = v.u;
    x += 0x7fffu + ((x >> 16) & 1u);
    return (u16)(x >> 16);
}
__device__ __forceinline__ float sigm(float x) { return 1.f / (1.f + __expf(-x)); }
__device__ __forceinline__ float tanh_f(float x) { return 2.f / (1.f + __expf(-2.f * x)) - 1.f; }

// ---------------------------------------------------------------------------
// dtype detector: l0_Wh is uniform(-1/32, 1/32). Genuine bf16 -> exponent
// field always < 127. fp32 bits misread as bf16 -> odd u16s are fp32 mantissa
// bits, ~50% have exponent >= 127. flag=1 means inputs are fp32.
// ---------------------------------------------------------------------------
__global__ void detect_dtype(const u16* __restrict__ w, int* __restrict__ flag) {
    __shared__ int s;
    if (threadIdx.x == 0) s = 0;
    __syncthreads();
    int bad = 0;
    for (int i = threadIdx.x; i < 4096; i += 256) {
        int e = (w[i] >> 7) & 0xff;
        if (e >= 127) bad = 1;
    }
    if (bad) atomicOr(&s, 1);
    __syncthreads();
    if (threadIdx.x == 0) *flag = s;
}

// ---------------------------------------------------------------------------
// convert 7 tensors (x + 6 bias vectors) to clean bf16, branching on flag
// ---------------------------------------------------------------------------
struct CvtList { const void* s[7]; u16* d[7]; int n[7]; };

__global__ void convert7(CvtList C, const int* __restrict__ flag) {
    const int fp32 = *flag;
    const int z = blockIdx.y;
    const int n = C.n[z];
    const int stride = gridDim.x * 256;
    for (int i = blockIdx.x * 256 + threadIdx.x; i < n; i += stride) {
        u16 o;
        if (fp32) o = f2b(((const float*)C.s[z])[i]);
        else      o = ((const u16*)C.s[z])[i];
        C.d[z][i] = o;
    }
}

// ---------------------------------------------------------------------------
// transpose 10 weight matrices [R,C] -> [C,R] bf16 out, dtype branch on read,
// per-entry element offset (for the depth-1 slices of the [2,H,H] tensors)
// ---------------------------------------------------------------------------
struct TListO {
    const void* s[10];
    u16*        d[10];
    int         R[10];
    int         Cc[10];
    long        off[10];
};

__global__ void transpose10(TListO L, const int* __restrict__ flag) {
    const int fp32 = *flag;
    const int z = blockIdx.z;
    const void* src = L.s[z];
    u16*        dst = L.d[z];
    const int R  = L.R[z];
    const int Cc = L.Cc[z];
    const long zo = L.off[z];
    const int tr = blockIdx.y * 32, tc = blockIdx.x * 32;
    if (tr >= R || tc >= Cc) return;           // block-uniform
    __align__(16) __shared__ u16 t[32][33];
    const int tx = threadIdx.x, ty = threadIdx.y;   // (32,8)
#pragma unroll
    for (int i = 0; i < 4; ++i) {
        const int r = ty + i * 8;
        const long e = zo + (long)(tr + r) * Cc + tc + tx;
        u16 v;
        if (fp32) v = f2b(((const float*)src)[e]);
        else      v = ((const u16*)src)[e];
        t[r][tx] = v;
    }
    __syncthreads();
#pragma unroll
    for (int i = 0; i < 4; ++i) {
        const int r = ty + i * 8;
        dst[(size_t)(tc + r) * R + tr + tx] = t[tx][r];
    }
}

// ---------------------------------------------------------------------------
// 128x128-tile bf16 MFMA GEMM, BK=32, register-mediated LDS staging (bisects
// out global_load_lds), bias epilogue.
// A: [M,K] row-major bf16.  BT: [N,K] row-major (B transposed). C = A@B + bias.
// ---------------------------------------------------------------------------
__global__ __launch_bounds__(256, 2) void gemm128(
    const u16* __restrict__ A, const u16* __restrict__ BT,
    const u16* __restrict__ bias, u16* __restrict__ C,
    int M, int N, int K)
{
    __align__(16) __shared__ u16 As[128 * 32];
    __align__(16) __shared__ u16 Bs[128 * 32];

    const int tid  = threadIdx.x;
    const int lane = tid & 63;
    const int wid  = tid >> 6;
    const int wr   = wid >> 1;
    const int wc   = wid & 1;

    const int n0 = blockIdx.x * 128;
    const int m0 = blockIdx.y * 128;

    floatx4 acc[4][4] = {};

    // staging: thread t loads rows r0 and r0+64, 8 u16 at k-offset kc
    const int r0 = tid >> 2;          // 0..63
    const int kc = (tid & 3) * 8;     // 0,8,16,24
    const u16* pA0 = A  + (size_t)(m0 + r0) * K + kc;
    const u16* pA1 = A  + (size_t)(m0 + r0 + 64) * K + kc;
    const u16* pB0 = BT + (size_t)(n0 + r0) * K + kc;
    const u16* pB1 = BT + (size_t)(n0 + r0 + 64) * K + kc;
    u16* sA0 = As + r0 * 32 + kc;
    u16* sA1 = As + (r0 + 64) * 32 + kc;
    u16* sB0 = Bs + r0 * 32 + kc;
    u16* sB1 = Bs + (r0 + 64) * 32 + kc;

    const int quad = lane >> 4;
    const int l16  = lane & 15;

    const int nk = K >> 5;
    for (int kt = 0; kt < nk; ++kt) {
        uint4 a0 = *(const uint4*)pA0;  pA0 += 32;
        uint4 a1 = *(const uint4*)pA1;  pA1 += 32;
        uint4 b0 = *(const uint4*)pB0;  pB0 += 32;
        uint4 b1 = *(const uint4*)pB1;  pB1 += 32;
        __syncthreads();               // previous iter's LDS reads done
        *(uint4*)sA0 = a0;
        *(uint4*)sA1 = a1;
        *(uint4*)sB0 = b0;
        *(uint4*)sB1 = b1;
        __syncthreads();

        bf16x8 af[4], bfr[4];
#pragma unroll
        for (int i = 0; i < 4; ++i) {
            af[i]  = *(const bf16x8*)(As + ((wr * 64 + i * 16 + l16) * 32 + quad * 8));
            bfr[i] = *(const bf16x8*)(Bs + ((wc * 64 + i * 16 + l16) * 32 + quad * 8));
        }
#pragma unroll
        for (int i = 0; i < 4; ++i)
#pragma unroll
            for (int j = 0; j < 4; ++j)
                acc[i][j] = __builtin_amdgcn_mfma_f32_16x16x32_bf16(af[i], bfr[j], acc[i][j], 0, 0, 0);
    }

#pragma unroll
    for (int i = 0; i < 4; ++i) {
        const int rowb = m0 + wr * 64 + i * 16 + quad * 4;
#pragma unroll
        for (int j = 0; j < 4; ++j) {
            const int col = n0 + wc * 64 + j * 16 + l16;
            const float bv = b2f(bias[col]);
#pragma unroll
            for (int r = 0; r < 4; ++r)
                C[(size_t)(rowb + r) * N + col] = f2b(acc[i][j][r] + bv);
        }
    }
}

// ---------------------------------------------------------------------------
// Fused highway GEMM: dual accumulators (t-gate, h-layer share A tile);
// epilogue h_new = h_old + sig(t)*(tanh(h)-h_old), h_old re-read from A.
// ---------------------------------------------------------------------------
__global__ __launch_bounds__(256, 2) void gemm_hw(
    const u16* __restrict__ A,      // [M,K] = h
    const u16* __restrict__ WtT,    // [N,K]
    const u16* __restrict__ WhT,    // [N,K]
    const u16* __restrict__ bt, const u16* __restrict__ bh,
    u16* __restrict__ Hout,
    int M, int N, int K)
{
    __align__(16) __shared__ u16 As [128 * 32];
    __align__(16) __shared__ u16 Bts[128 * 32];
    __align__(16) __shared__ u16 Bhs[128 * 32];

    const int tid  = threadIdx.x;
    const int lane = tid & 63;
    const int wid  = tid >> 6;
    const int wr   = wid >> 1;
    const int wc   = wid & 1;

    const int n0 = blockIdx.x * 128;
    const int m0 = blockIdx.y * 128;

    floatx4 acct[4][4] = {};
    floatx4 acch[4][4] = {};

    const int r0 = tid >> 2;
    const int kc = (tid & 3) * 8;
    const u16* pA0 = A   + (size_t)(m0 + r0) * K + kc;
    const u16* pA1 = A   + (size_t)(m0 + r0 + 64) * K + kc;
    const u16* pT0 = WtT + (size_t)(n0 + r0) * K + kc;
    const u16* pT1 = WtT + (size_t)(n0 + r0 + 64) * K + kc;
    const u16* pH0 = WhT + (size_t)(n0 + r0) * K + kc;
    const u16* pH1 = WhT + (size_t)(n0 + r0 + 64) * K + kc;
    u16* sA0 = As  + r0 * 32 + kc;
    u16* sA1 = As  + (r0 + 64) * 32 + kc;
    u16* sT0 = Bts + r0 * 32 + kc;
    u16* sT1 = Bts + (r0 + 64) * 32 + kc;
    u16* sH0 = Bhs + r0 * 32 + kc;
    u16* sH1 = Bhs + (r0 + 64) * 32 + kc;

    const int quad = lane >> 4;
    const int l16  = lane & 15;

    const int nk = K >> 5;
    for (int kt = 0; kt < nk; ++kt) {
        uint4 a0 = *(const uint4*)pA0;  pA0 += 32;
        uint4 a1 = *(const uint4*)pA1;  pA1 += 32;
        uint4 t0 = *(const uint4*)pT0;  pT0 += 32;
        uint4 t1 = *(const uint4*)pT1;  pT1 += 32;
        uint4 h0 = *(const uint4*)pH0;  pH0 += 32;
        uint4 h1 = *(const uint4*)pH1;  pH1 += 32;
        __syncthreads();
        *(uint4*)sA0 = a0;
        *(uint4*)sA1 = a1;
        *(uint4*)sT0 = t0;
        *(uint4*)sT1 = t1;
        *(uint4*)sH0 = h0;
        *(uint4*)sH1 = h1;
        __syncthreads();

        bf16x8 af[4], btf[4], bhf[4];
#pragma unroll
        for (int i = 0; i < 4; ++i) {
            af[i]  = *(const bf16x8*)(As  + ((wr * 64 + i * 16 + l16) * 32 + quad * 8));
            btf[i] = *(const bf16x8*)(Bts + ((wc * 64 + i * 16 + l16) * 32 + quad * 8));
            bhf[i] = *(const bf16x8*)(Bhs + ((wc * 64 + i * 16 + l16) * 32 + quad * 8));
        }
#pragma unroll
        for (int i = 0; i < 4; ++i)
#pragma unroll
            for (int j = 0; j < 4; ++j) {
                acct[i][j] = __builtin_amdgcn_mfma_f32_16x16x32_bf16(af[i], btf[j], acct[i][j], 0, 0, 0);
                acch[i][j] = __builtin_amdgcn_mfma_f32_16x16x32_bf16(af[i], bhf[j], acch[i][j], 0, 0, 0);
            }
    }

#pragma unroll
    for (int i = 0; i < 4; ++i) {
        const int rowb = m0 + wr * 64 + i * 16 + quad * 4;
#pragma unroll
        for (int j = 0; j < 4; ++j) {
            const int col = n0 + wc * 64 + j * 16 + l16;
            const float btv = b2f(bt[col]);
            const float bhv = b2f(bh[col]);
#pragma unroll
            for (int r = 0; r < 4; ++r) {
                const size_t idx = (size_t)(rowb + r) * N + col;
                const float hold = b2f(A[idx]);
                const float tg = sigm(acct[i][j][r] + btv);
                const float hl = tanh_f(acch[i][j][r] + bhv);
                Hout[idx] = f2b(hold + tg * (hl - hold));
            }
        }
    }
}

// ---------------------------------------------------------------------------
// in-place cumsum over t (fp32 accumulate): g is [B=64, T=256, H=1024] bf16
// ---------------------------------------------------------------------------
__global__ void cumsum_t(u16* g) {
    const int id = blockIdx.x * 256 + threadIdx.x;  // 65536 = B*H
    const int b = id >> 10, f = id & 1023;
    size_t base = (size_t)b * SEQ * HID + f;
    float acc = 0.f;
#pragma unroll 4
    for (int t = 0; t < SEQ; ++t) {
        size_t idx = base + (size_t)t * HID;
        acc += b2f(g[idx]);
        g[idx] = f2b(acc);
    }
}

// sum over t -> fp32 [B, H]
__global__ void sum_t(const u16* __restrict__ g, float* __restrict__ out) {
    const int id = blockIdx.x * 256 + threadIdx.x;  // 65536
    const int b = id >> 10, f = id & 1023;
    size_t base = (size_t)b * SEQ * HID + f;
    float acc = 0.f;
#pragma unroll 4
    for (int t = 0; t < SEQ; ++t)
        acc += b2f(g[base + (size_t)t * HID]);
    out[id] = acc;
}

// final fc, dtype-branched on both W/bias reads and the output write
__global__ void fc_final(const float* __restrict__ hf, const void* __restrict__ W,
                         const void* __restrict__ bias, void* __restrict__ out,
                         const int* __restrict__ flag) {
    __shared__ float sh[HID];
    const int fp32 = *flag;
    const int b = blockIdx.x, o = threadIdx.x;      // 64 blocks x 128 threads
    for (int k = o; k < HID; k += 128) sh[k] = hf[(size_t)b * HID + k];
    __syncthreads();
    float acc;
    if (fp32) {
        acc = ((const float*)bias)[o];
        for (int k = 0; k < HID; ++k)
            acc += sh[k] * ((const float*)W)[(size_t)k * OUTDIM + o];
        ((float*)out)[b * OUTDIM + o] = acc;
    } else {
        acc = b2f(((const u16*)bias)[o]);
        for (int k = 0; k < HID; ++k)
            acc += sh[k] * b2f(((const u16*)W)[(size_t)k * OUTDIM + o]);
        ((u16*)out)[b * OUTDIM + o] = f2b(acc);
    }
}

// ---------------------------------------------------------------------------
extern "C" void kernel_launch(void* const* d_in, const int* in_sizes, int n_in,
                              void* d_out, int out_size, void* d_ws, size_t ws_size,
                              hipStream_t stream) {
    const void* x      = d_in[0];
    const void* l0_Win = d_in[1];
    const void* l0_bin = d_in[2];
    const void* l0_Wh  = d_in[3];
    const void* l0_bh  = d_in[4];
    const void* l0_Wt  = d_in[5];
    const void* l0_bt  = d_in[6];
    const void* l1_Win = d_in[7];
    const void* l1_bin = d_in[8];
    const void* l1_Wh  = d_in[9];
    const void* l1_bh  = d_in[10];
    const void* l1_Wt  = d_in[11];
    const void* l1_bt  = d_in[12];
    const void* fc_W   = d_in[13];
    const void* fc_b   = d_in[14];

    char* ws = (char*)d_ws;
    u16* Pa = (u16*)(ws);                       // 32 MB; hfinal reuses its base at the tail
    u16* Pb = (u16*)(ws + 33554432);            // 32 MB; x-clean occupies its first 4 MB
    u16* xc = Pb;                               // [16384,128] clean bf16 x
    u16* tW = (u16*)(ws + 67108864);
    u16* tWin0 = tW;                  // [1024,128]
    u16* tWt00 = tWin0 + 131072;      // each [1024,1024]
    u16* tWt01 = tWt00 + 1048576;
    u16* tWh00 = tWt01 + 1048576;
    u16* tWh01 = tWh00 + 1048576;
    u16* tWin1 = tWh01 + 1048576;
    u16* tWt10 = tWin1 + 1048576;
    u16* tWt11 = tWt10 + 1048576;
    u16* tWh10 = tWt11 + 1048576;
    u16* tWh11 = tWh10 + 1048576;
    u16* smallb = tWh11 + 1048576;    // bias copies: 10240 elems
    u16* binc0 = smallb;              // 1024
    u16* bhc0  = binc0 + 1024;        // 2048 (both depths)
    u16* btc0  = bhc0 + 2048;         // 2048
    u16* binc1 = btc0 + 2048;         // 1024
    u16* bhc1  = binc1 + 1024;        // 2048
    u16* btc1  = bhc1 + 2048;         // 2048
    int* flag  = (int*)(btc1 + 2048);
    float* hfinal = (float*)Pa;       // [64,1024] fp32, Pa free by then

    detect_dtype<<<1, 256, 0, stream>>>((const u16*)l0_Wh, flag);

    const long DD = (long)HID * HID;   // element offset of depth-1 slice
    TListO L;
    L.s[0] = l0_Win; L.d[0] = tWin0; L.R[0] = INDIM; L.Cc[0] = HID; L.off[0] = 0;
    L.s[1] = l0_Wt;  L.d[1] = tWt00; L.R[1] = HID;   L.Cc[1] = HID; L.off[1] = 0;
    L.s[2] = l0_Wt;  L.d[2] = tWt01; L.R[2] = HID;   L.Cc[2] = HID; L.off[2] = DD;
    L.s[3] = l0_Wh;  L.d[3] = tWh00; L.R[3] = HID;   L.Cc[3] = HID; L.off[3] = 0;
    L.s[4] = l0_Wh;  L.d[4] = tWh01; L.R[4] = HID;   L.Cc[4] = HID; L.off[4] = DD;
    L.s[5] = l1_Win; L.d[5] = tWin1; L.R[5] = HID;   L.Cc[5] = HID; L.off[5] = 0;
    L.s[6] = l1_Wt;  L.d[6] = tWt10; L.R[6] = HID;   L.Cc[6] = HID; L.off[6] = 0;
    L.s[7] = l1_Wt;  L.d[7] = tWt11; L.R[7] = HID;   L.Cc[7] = HID; L.off[7] = DD;
    L.s[8] = l1_Wh;  L.d[8] = tWh10; L.R[8] = HID;   L.Cc[8] = HID; L.off[8] = 0;
    L.s[9] = l1_Wh;  L.d[9] = tWh11; L.R[9] = HID;   L.Cc[9] = HID; L.off[9] = DD;
    transpose10<<<dim3(32, 32, 10), dim3(32, 8), 0, stream>>>(L, flag);

    CvtList C7;
    C7.s[0] = x;      C7.d[0] = xc;    C7.n[0] = MROWS * INDIM;
    C7.s[1] = l0_bin; C7.d[1] = binc0; C7.n[1] = HID;
    C7.s[2] = l0_bh;  C7.d[2] = bhc0;  C7.n[2] = 2 * HID;
    C7.s[3] = l0_bt;  C7.d[3] = btc0;  C7.n[3] = 2 * HID;
    C7.s[4] = l1_bin; C7.d[4] = binc1; C7.n[4] = HID;
    C7.s[5] = l1_bh;  C7.d[5] = bhc1;  C7.n[5] = 2 * HID;
    C7.s[6] = l1_bt;  C7.d[6] = btc1;  C7.n[6] = 2 * HID;
    convert7<<<dim3(512, 7), 256, 0, stream>>>(C7, flag);

    // ---- layer 0 ----
    gemm128<<<dim3(8, 128), 256, 0, stream>>>(xc, tWin0, binc0, Pa, MROWS, HID, INDIM);
    gemm_hw<<<dim3(8, 128), 256, 0, stream>>>(Pa, tWt00, tWh00, btc0, bhc0, Pb, MROWS, HID, HID);
    gemm_hw<<<dim3(8, 128), 256, 0, stream>>>(Pb, tWt01, tWh01, btc0 + HID, bhc0 + HID, Pa, MROWS, HID, HID);
    cumsum_t<<<256, 256, 0, stream>>>(Pa);      // Pa = y0

    // ---- layer 1 ----
    gemm128<<<dim3(8, 128), 256, 0, stream>>>(Pa, tWin1, binc1, Pb, MROWS, HID, HID);
    gemm_hw<<<dim3(8, 128), 256, 0, stream>>>(Pb, tWt10, tWh10, btc1, bhc1, Pa, MROWS, HID, HID);
    gemm_hw<<<dim3(8, 128), 256, 0, stream>>>(Pa, tWt11, tWh11, btc1 + HID, bhc1 + HID, Pb, MROWS, HID, HID);

    // ---- tail ----
    sum_t<<<256, 256, 0, stream>>>(Pb, hfinal);
    fc_final<<<64, 128, 0, stream>>>(hfinal, fc_W, fc_b, d_out, flag);
}

// Round 5
// 621.029 us; speedup vs baseline: 1.0001x; 1.0001x over previous
//
#include <hip/hip_runtime.h>

typedef unsigned short u16;
typedef unsigned int u32;
typedef __bf16 bf16x8 __attribute__((ext_vector_type(8)));
typedef float floatx4 __attribute__((ext_vector_type(4)));

#define HID 1024
#define BATCH 64
#define SEQ 256
#define INDIM 128
#define OUTDIM 128
#define MROWS (BATCH*SEQ)   // 16384

__device__ __forceinline__ float b2f(u16 u) {
    union { u32 u; float f; } v; v.u = ((u32)u) << 16; return v.f;
}
__device__ __forceinline__ u16 f2b(float f) {
    union { float f; u32 u; } v; v.f = f;
    u32 x = v.u;
    x += 0x7fffu + ((x >> 16) & 1u);
    return (u16)(x >> 16);
}
__device__ __forceinline__ float sigm(float x) { return 1.f / (1.f + __expf(-x)); }
__device__ __forceinline__ float tanh_f(float x) { return 2.f / (1.f + __expf(-2.f * x)) - 1.f; }

__device__ __forceinline__ void gld16(const u16* g, u16* l) {
    __builtin_amdgcn_global_load_lds(
        (const __attribute__((address_space(1))) void*)g,
        (__attribute__((address_space(3))) void*)l, 16, 0, 0);
}

// ---------------------------------------------------------------------------
// dtype detector: l0_Wh is uniform(-1/32, 1/32). Genuine bf16 -> exponent
// field always < 127. fp32 bits misread as bf16 -> odd u16s are fp32 mantissa
// bits, ~50% have exponent >= 127. flag=1 means inputs are fp32.
// ---------------------------------------------------------------------------
__global__ void detect_dtype(const u16* __restrict__ w, int* __restrict__ flag) {
    __shared__ int s;
    if (threadIdx.x == 0) s = 0;
    __syncthreads();
    int bad = 0;
    for (int i = threadIdx.x; i < 4096; i += 256) {
        int e = (w[i] >> 7) & 0xff;
        if (e >= 127) bad = 1;
    }
    if (bad) atomicOr(&s, 1);
    __syncthreads();
    if (threadIdx.x == 0) *flag = s;
}

// ---------------------------------------------------------------------------
// convert 7 tensors (x + 6 bias vectors) to clean bf16, branching on flag
// ---------------------------------------------------------------------------
struct CvtList { const void* s[7]; u16* d[7]; int n[7]; };

__global__ void convert7(CvtList C, const int* __restrict__ flag) {
    const int fp32 = *flag;
    const int z = blockIdx.y;
    const int n = C.n[z];
    const int stride = gridDim.x * 256;
    for (int i = blockIdx.x * 256 + threadIdx.x; i < n; i += stride) {
        u16 o;
        if (fp32) o = f2b(((const float*)C.s[z])[i]);
        else      o = ((const u16*)C.s[z])[i];
        C.d[z][i] = o;
    }
}

// ---------------------------------------------------------------------------
// transpose 10 weight matrices [R,C] -> [C,R] bf16 out, dtype branch on read,
// per-entry element offset (for the depth-1 slices of the [2,H,H] tensors)
// ---------------------------------------------------------------------------
struct TListO {
    const void* s[10];
    u16*        d[10];
    int         R[10];
    int         Cc[10];
    long        off[10];
};

__global__ void transpose10(TListO L, const int* __restrict__ flag) {
    const int fp32 = *flag;
    const int z = blockIdx.z;
    const void* src = L.s[z];
    u16*        dst = L.d[z];
    const int R  = L.R[z];
    const int Cc = L.Cc[z];
    const long zo = L.off[z];
    const int tr = blockIdx.y * 32, tc = blockIdx.x * 32;
    if (tr >= R || tc >= Cc) return;           // block-uniform
    __align__(16) __shared__ u16 t[32][33];
    const int tx = threadIdx.x, ty = threadIdx.y;   // (32,8)
#pragma unroll
    for (int i = 0; i < 4; ++i) {
        const int r = ty + i * 8;
        const long e = zo + (long)(tr + r) * Cc + tc + tx;
        u16 v;
        if (fp32) v = f2b(((const float*)src)[e]);
        else      v = ((const u16*)src)[e];
        t[r][tx] = v;
    }
    __syncthreads();
#pragma unroll
    for (int i = 0; i < 4; ++i) {
        const int r = ty + i * 8;
        dst[(size_t)(tc + r) * R + tr + tx] = t[tx][r];
    }
}

// ---------------------------------------------------------------------------
// 128x128-tile bf16 MFMA GEMM, BK=32, global_load_lds width-16 staging,
// bias epilogue.
// A: [M,K] row-major bf16.  BT: [N,K] row-major (B transposed). C = A@B + bias.
// Staging layout (per wave, chunk c0=wid*2): lane i -> row c0*16+(i>>2),
// cols (i&3)*8..+8 ; LDS dest = base + i*16B (wave-uniform base). Verified
// against the m104/m108 constraint.
// ---------------------------------------------------------------------------
__global__ __launch_bounds__(256, 2) void gemm128(
    const u16* __restrict__ A, const u16* __restrict__ BT,
    const u16* __restrict__ bias, u16* __restrict__ C,
    int M, int N, int K)
{
    __align__(16) __shared__ u16 As[128 * 32];
    __align__(16) __shared__ u16 Bs[128 * 32];

    const int tid  = threadIdx.x;
    const int lane = tid & 63;
    const int wid  = tid >> 6;
    const int wr   = wid >> 1;
    const int wc   = wid & 1;

    const int n0 = blockIdx.x * 128;
    const int m0 = blockIdx.y * 128;

    floatx4 acc[4][4] = {};

    const int c0    = wid * 2;
    const int srow  = c0 * 16 + (lane >> 2);
    const int skcol = (lane & 3) * 8;
    const u16* Ag  = A  + (size_t)(m0 + srow) * K + skcol;
    const u16* Ag2 = A  + (size_t)(m0 + srow + 16) * K + skcol;
    const u16* Bg  = BT + (size_t)(n0 + srow) * K + skcol;
    const u16* Bg2 = BT + (size_t)(n0 + srow + 16) * K + skcol;
    u16* Asl  = As + c0 * 512;        // wave-uniform LDS dests
    u16* Asl2 = As + (c0 + 1) * 512;
    u16* Bsl  = Bs + c0 * 512;
    u16* Bsl2 = Bs + (c0 + 1) * 512;

    const int quad = lane >> 4;
    const int l16  = lane & 15;

    const int nk = K >> 5;
    for (int kt = 0; kt < nk; ++kt) {
        __syncthreads();                 // previous iter's LDS reads done
        gld16(Ag,  Asl);  gld16(Ag2, Asl2);
        gld16(Bg,  Bsl);  gld16(Bg2, Bsl2);
        Ag += 32; Ag2 += 32; Bg += 32; Bg2 += 32;
        __syncthreads();                 // drains vmcnt (DMA) before compute

        bf16x8 af[4], bfr[4];
#pragma unroll
        for (int i = 0; i < 4; ++i) {
            af[i]  = *(const bf16x8*)(As + ((wr * 64 + i * 16 + l16) * 32 + quad * 8));
            bfr[i] = *(const bf16x8*)(Bs + ((wc * 64 + i * 16 + l16) * 32 + quad * 8));
        }
#pragma unroll
        for (int i = 0; i < 4; ++i)
#pragma unroll
            for (int j = 0; j < 4; ++j)
                acc[i][j] = __builtin_amdgcn_mfma_f32_16x16x32_bf16(af[i], bfr[j], acc[i][j], 0, 0, 0);
    }

#pragma unroll
    for (int i = 0; i < 4; ++i) {
        const int rowb = m0 + wr * 64 + i * 16 + quad * 4;
#pragma unroll
        for (int j = 0; j < 4; ++j) {
            const int col = n0 + wc * 64 + j * 16 + l16;
            const float bv = b2f(bias[col]);
#pragma unroll
            for (int r = 0; r < 4; ++r)
                C[(size_t)(rowb + r) * N + col] = f2b(acc[i][j][r] + bv);
        }
    }
}

// ---------------------------------------------------------------------------
// Fused highway GEMM: dual accumulators (t-gate, h-layer share A tile);
// epilogue h_new = h_old + sig(t)*(tanh(h)-h_old), h_old re-read from A.
// global_load_lds staging, 3 tensors (A, WtT, WhT), 24 KB LDS.
// ---------------------------------------------------------------------------
__global__ __launch_bounds__(256, 2) void gemm_hw(
    const u16* __restrict__ A,      // [M,K] = h
    const u16* __restrict__ WtT,    // [N,K]
    const u16* __restrict__ WhT,    // [N,K]
    const u16* __restrict__ bt, const u16* __restrict__ bh,
    u16* __restrict__ Hout,
    int M, int N, int K)
{
    __align__(16) __shared__ u16 As [128 * 32];
    __align__(16) __shared__ u16 Bts[128 * 32];
    __align__(16) __shared__ u16 Bhs[128 * 32];

    const int tid  = threadIdx.x;
    const int lane = tid & 63;
    const int wid  = tid >> 6;
    const int wr   = wid >> 1;
    const int wc   = wid & 1;

    const int n0 = blockIdx.x * 128;
    const int m0 = blockIdx.y * 128;

    floatx4 acct[4][4] = {};
    floatx4 acch[4][4] = {};

    const int c0    = wid * 2;
    const int srow  = c0 * 16 + (lane >> 2);
    const int skcol = (lane & 3) * 8;
    const u16* Ag   = A   + (size_t)(m0 + srow) * K + skcol;
    const u16* Ag2  = A   + (size_t)(m0 + srow + 16) * K + skcol;
    const u16* Btg  = WtT + (size_t)(n0 + srow) * K + skcol;
    const u16* Btg2 = WtT + (size_t)(n0 + srow + 16) * K + skcol;
    const u16* Bhg  = WhT + (size_t)(n0 + srow) * K + skcol;
    const u16* Bhg2 = WhT + (size_t)(n0 + srow + 16) * K + skcol;
    u16* Asl  = As  + c0 * 512;
    u16* Asl2 = As  + (c0 + 1) * 512;
    u16* Btl  = Bts + c0 * 512;
    u16* Btl2 = Bts + (c0 + 1) * 512;
    u16* Bhl  = Bhs + c0 * 512;
    u16* Bhl2 = Bhs + (c0 + 1) * 512;

    const int quad = lane >> 4;
    const int l16  = lane & 15;

    const int nk = K >> 5;
    for (int kt = 0; kt < nk; ++kt) {
        __syncthreads();
        gld16(Ag,  Asl);   gld16(Ag2,  Asl2);
        gld16(Btg, Btl);   gld16(Btg2, Btl2);
        gld16(Bhg, Bhl);   gld16(Bhg2, Bhl2);
        Ag += 32; Ag2 += 32; Btg += 32; Btg2 += 32; Bhg += 32; Bhg2 += 32;
        __syncthreads();

        bf16x8 af[4], btf[4], bhf[4];
#pragma unroll
        for (int i = 0; i < 4; ++i) {
            af[i]  = *(const bf16x8*)(As  + ((wr * 64 + i * 16 + l16) * 32 + quad * 8));
            btf[i] = *(const bf16x8*)(Bts + ((wc * 64 + i * 16 + l16) * 32 + quad * 8));
            bhf[i] = *(const bf16x8*)(Bhs + ((wc * 64 + i * 16 + l16) * 32 + quad * 8));
        }
#pragma unroll
        for (int i = 0; i < 4; ++i)
#pragma unroll
            for (int j = 0; j < 4; ++j) {
                acct[i][j] = __builtin_amdgcn_mfma_f32_16x16x32_bf16(af[i], btf[j], acct[i][j], 0, 0, 0);
                acch[i][j] = __builtin_amdgcn_mfma_f32_16x16x32_bf16(af[i], bhf[j], acch[i][j], 0, 0, 0);
            }
    }

#pragma unroll
    for (int i = 0; i < 4; ++i) {
        const int rowb = m0 + wr * 64 + i * 16 + quad * 4;
#pragma unroll
        for (int j = 0; j < 4; ++j) {
            const int col = n0 + wc * 64 + j * 16 + l16;
            const float btv = b2f(bt[col]);
            const float bhv = b2f(bh[col]);
#pragma unroll
            for (int r = 0; r < 4; ++r) {
                const size_t idx = (size_t)(rowb + r) * N + col;
                const float hold = b2f(A[idx]);
                const float tg = sigm(acct[i][j][r] + btv);
                const float hl = tanh_f(acch[i][j][r] + bhv);
                Hout[idx] = f2b(hold + tg * (hl - hold));
            }
        }
    }
}

// ---------------------------------------------------------------------------
// in-place cumsum over t (fp32 accumulate): g is [B=64, T=256, H=1024] bf16
// ---------------------------------------------------------------------------
__global__ void cumsum_t(u16* g) {
    const int id = blockIdx.x * 256 + threadIdx.x;  // 65536 = B*H
    const int b = id >> 10, f = id & 1023;
    size_t base = (size_t)b * SEQ * HID + f;
    float acc = 0.f;
#pragma unroll 4
    for (int t = 0; t < SEQ; ++t) {
        size_t idx = base + (size_t)t * HID;
        acc += b2f(g[idx]);
        g[idx] = f2b(acc);
    }
}

// sum over t -> fp32 [B, H]
__global__ void sum_t(const u16* __restrict__ g, float* __restrict__ out) {
    const int id = blockIdx.x * 256 + threadIdx.x;  // 65536
    const int b = id >> 10, f = id & 1023;
    size_t base = (size_t)b * SEQ * HID + f;
    float acc = 0.f;
#pragma unroll 4
    for (int t = 0; t < SEQ; ++t)
        acc += b2f(g[base + (size_t)t * HID]);
    out[id] = acc;
}

// final fc, dtype-branched on both W/bias reads and the output write
__global__ void fc_final(const float* __restrict__ hf, const void* __restrict__ W,
                         const void* __restrict__ bias, void* __restrict__ out,
                         const int* __restrict__ flag) {
    __shared__ float sh[HID];
    const int fp32 = *flag;
    const int b = blockIdx.x, o = threadIdx.x;      // 64 blocks x 128 threads
    for (int k = o; k < HID; k += 128) sh[k] = hf[(size_t)b * HID + k];
    __syncthreads();
    float acc;
    if (fp32) {
        acc = ((const float*)bias)[o];
        for (int k = 0; k < HID; ++k)
            acc += sh[k] * ((const float*)W)[(size_t)k * OUTDIM + o];
        ((float*)out)[b * OUTDIM + o] = acc;
    } else {
        acc = b2f(((const u16*)bias)[o]);
        for (int k = 0; k < HID; ++k)
            acc += sh[k] * b2f(((const u16*)W)[(size_t)k * OUTDIM + o]);
        ((u16*)out)[b * OUTDIM + o] = f2b(acc);
    }
}

// ---------------------------------------------------------------------------
extern "C" void kernel_launch(void* const* d_in, const int* in_sizes, int n_in,
                              void* d_out, int out_size, void* d_ws, size_t ws_size,
                              hipStream_t stream) {
    const void* x      = d_in[0];
    const void* l0_Win = d_in[1];
    const void* l0_bin = d_in[2];
    const void* l0_Wh  = d_in[3];
    const void* l0_bh  = d_in[4];
    const void* l0_Wt  = d_in[5];
    const void* l0_bt  = d_in[6];
    const void* l1_Win = d_in[7];
    const void* l1_bin = d_in[8];
    const void* l1_Wh  = d_in[9];
    const void* l1_bh  = d_in[10];
    const void* l1_Wt  = d_in[11];
    const void* l1_bt  = d_in[12];
    const void* fc_W   = d_in[13];
    const void* fc_b   = d_in[14];

    char* ws = (char*)d_ws;
    u16* Pa = (u16*)(ws);                       // 32 MB; hfinal reuses its base at the tail
    u16* Pb = (u16*)(ws + 33554432);            // 32 MB; x-clean occupies its first 4 MB
    u16* xc = Pb;                               // [16384,128] clean bf16 x
    u16* tW = (u16*)(ws + 67108864);
    u16* tWin0 = tW;                  // [1024,128]
    u16* tWt00 = tWin0 + 131072;      // each [1024,1024]
    u16* tWt01 = tWt00 + 1048576;
    u16* tWh00 = tWt01 + 1048576;
    u16* tWh01 = tWh00 + 1048576;
    u16* tWin1 = tWh01 + 1048576;
    u16* tWt10 = tWin1 + 1048576;
    u16* tWt11 = tWt10 + 1048576;
    u16* tWh10 = tWt11 + 1048576;
    u16* tWh11 = tWh10 + 1048576;
    u16* smallb = tWh11 + 1048576;    // bias copies: 10240 elems
    u16* binc0 = smallb;              // 1024
    u16* bhc0  = binc0 + 1024;        // 2048 (both depths)
    u16* btc0  = bhc0 + 2048;         // 2048
    u16* binc1 = btc0 + 2048;         // 1024
    u16* bhc1  = binc1 + 1024;        // 2048
    u16* btc1  = bhc1 + 2048;         // 2048
    int* flag  = (int*)(btc1 + 2048);
    float* hfinal = (float*)Pa;       // [64,1024] fp32, Pa free by then

    detect_dtype<<<1, 256, 0, stream>>>((const u16*)l0_Wh, flag);

    const long DD = (long)HID * HID;   // element offset of depth-1 slice
    TListO L;
    L.s[0] = l0_Win; L.d[0] = tWin0; L.R[0] = INDIM; L.Cc[0] = HID; L.off[0] = 0;
    L.s[1] = l0_Wt;  L.d[1] = tWt00; L.R[1] = HID;   L.Cc[1] = HID; L.off[1] = 0;
    L.s[2] = l0_Wt;  L.d[2] = tWt01; L.R[2] = HID;   L.Cc[2] = HID; L.off[2] = DD;
    L.s[3] = l0_Wh;  L.d[3] = tWh00; L.R[3] = HID;   L.Cc[3] = HID; L.off[3] = 0;
    L.s[4] = l0_Wh;  L.d[4] = tWh01; L.R[4] = HID;   L.Cc[4] = HID; L.off[4] = DD;
    L.s[5] = l1_Win; L.d[5] = tWin1; L.R[5] = HID;   L.Cc[5] = HID; L.off[5] = 0;
    L.s[6] = l1_Wt;  L.d[6] = tWt10; L.R[6] = HID;   L.Cc[6] = HID; L.off[6] = 0;
    L.s[7] = l1_Wt;  L.d[7] = tWt11; L.R[7] = HID;   L.Cc[7] = HID; L.off[7] = DD;
    L.s[8] = l1_Wh;  L.d[8] = tWh10; L.R[8] = HID;   L.Cc[8] = HID; L.off[8] = 0;
    L.s[9] = l1_Wh;  L.d[9] = tWh11; L.R[9] = HID;   L.Cc[9] = HID; L.off[9] = DD;
    transpose10<<<dim3(32, 32, 10), dim3(32, 8), 0, stream>>>(L, flag);

    CvtList C7;
    C7.s[0] = x;      C7.d[0] = xc;    C7.n[0] = MROWS * INDIM;
    C7.s[1] = l0_bin; C7.d[1] = binc0; C7.n[1] = HID;
    C7.s[2] = l0_bh;  C7.d[2] = bhc0;  C7.n[2] = 2 * HID;
    C7.s[3] = l0_bt;  C7.d[3] = btc0;  C7.n[3] = 2 * HID;
    C7.s[4] = l1_bin; C7.d[4] = binc1; C7.n[4] = HID;
    C7.s[5] = l1_bh;  C7.d[5] = bhc1;  C7.n[5] = 2 * HID;
    C7.s[6] = l1_bt;  C7.d[6] = btc1;  C7.n[6] = 2 * HID;
    convert7<<<dim3(512, 7), 256, 0, stream>>>(C7, flag);

    // ---- layer 0 ----
    gemm128<<<dim3(8, 128), 256, 0, stream>>>(xc, tWin0, binc0, Pa, MROWS, HID, INDIM);
    gemm_hw<<<dim3(8, 128), 256, 0, stream>>>(Pa, tWt00, tWh00, btc0, bhc0, Pb, MROWS, HID, HID);
    gemm_hw<<<dim3(8, 128), 256, 0, stream>>>(Pb, tWt01, tWh01, btc0 + HID, bhc0 + HID, Pa, MROWS, HID, HID);
    cumsum_t<<<256, 256, 0, stream>>>(Pa);      // Pa = y0

    // ---- layer 1 ----
    gemm128<<<dim3(8, 128), 256, 0, stream>>>(Pa, tWin1, binc1, Pb, MROWS, HID, HID);
    gemm_hw<<<dim3(8, 128), 256, 0, stream>>>(Pb, tWt10, tWh10, btc1, bhc1, Pa, MROWS, HID, HID);
    gemm_hw<<<dim3(8, 128), 256, 0, stream>>>(Pa, tWt11, tWh11, btc1 + HID, bhc1 + HID, Pb, MROWS, HID, HID);

    // ---- tail ----
    sum_t<<<256, 256, 0, stream>>>(Pb, hfinal);
    fc_final<<<64, 128, 0, stream>>>(hfinal, fc_W, fc_b, d_out, flag);
}

// Round 6
// 513.610 us; speedup vs baseline: 1.2092x; 1.2091x over previous
//
#include <hip/hip_runtime.h>

typedef unsigned short u16;
typedef unsigned int u32;
typedef __bf16 bf16x8 __attribute__((ext_vector_type(8)));
typedef float floatx4 __attribute__((ext_vector_type(4)));

#define HID 1024
#define BATCH 64
#define SEQ 256
#define INDIM 128
#define OUTDIM 128
#define MROWS (BATCH*SEQ)   // 16384

__device__ __forceinline__ float b2f(u16 u) {
    union { u32 u; float f; } v; v.u = ((u32)u) << 16; return v.f;
}
__device__ __forceinline__ u16 f2b(float f) {
    union { float f; u32 u; } v; v.f = f;
    u32 x = v.u;
    x += 0x7fffu + ((x >> 16) & 1u);
    return (u16)(x >> 16);
}
__device__ __forceinline__ float sigm(float x) { return 1.f / (1.f + __expf(-x)); }
__device__ __forceinline__ float tanh_f(float x) { return 2.f / (1.f + __expf(-2.f * x)) - 1.f; }

__device__ __forceinline__ void gld16(const u16* g, u16* l) {
    __builtin_amdgcn_global_load_lds(
        (const __attribute__((address_space(1))) void*)g,
        (__attribute__((address_space(3))) void*)l, 16, 0, 0);
}

// ---------------------------------------------------------------------------
// dtype detector: l0_Wh is uniform(-1/32, 1/32). Genuine bf16 -> exponent
// field always < 127. fp32 bits misread as bf16 -> ~50% have exponent >= 127.
// flag=1 means inputs are fp32.
// ---------------------------------------------------------------------------
__global__ void detect_dtype(const u16* __restrict__ w, int* __restrict__ flag) {
    __shared__ int s;
    if (threadIdx.x == 0) s = 0;
    __syncthreads();
    int bad = 0;
    for (int i = threadIdx.x; i < 4096; i += 256) {
        int e = (w[i] >> 7) & 0xff;
        if (e >= 127) bad = 1;
    }
    if (bad) atomicOr(&s, 1);
    __syncthreads();
    if (threadIdx.x == 0) *flag = s;
}

// ---------------------------------------------------------------------------
// convert 7 tensors (x + 6 bias vectors) to clean bf16, branching on flag
// ---------------------------------------------------------------------------
struct CvtList { const void* s[7]; u16* d[7]; int n[7]; };

__global__ void convert7(CvtList C, const int* __restrict__ flag) {
    const int fp32 = *flag;
    const int z = blockIdx.y;
    const int n = C.n[z];
    const int stride = gridDim.x * 256;
    for (int i = blockIdx.x * 256 + threadIdx.x; i < n; i += stride) {
        u16 o;
        if (fp32) o = f2b(((const float*)C.s[z])[i]);
        else      o = ((const u16*)C.s[z])[i];
        C.d[z][i] = o;
    }
}

// ---------------------------------------------------------------------------
// transpose 10 weight matrices [R,C] -> [C,R] bf16 out, dtype branch on read,
// per-entry element offset (for the depth-1 slices of the [2,H,H] tensors)
// ---------------------------------------------------------------------------
struct TListO {
    const void* s[10];
    u16*        d[10];
    int         R[10];
    int         Cc[10];
    long        off[10];
};

__global__ void transpose10(TListO L, const int* __restrict__ flag) {
    const int fp32 = *flag;
    const int z = blockIdx.z;
    const void* src = L.s[z];
    u16*        dst = L.d[z];
    const int R  = L.R[z];
    const int Cc = L.Cc[z];
    const long zo = L.off[z];
    const int tr = blockIdx.y * 32, tc = blockIdx.x * 32;
    if (tr >= R || tc >= Cc) return;           // block-uniform
    __align__(16) __shared__ u16 t[32][33];
    const int tx = threadIdx.x, ty = threadIdx.y;   // (32,8)
#pragma unroll
    for (int i = 0; i < 4; ++i) {
        const int r = ty + i * 8;
        const long e = zo + (long)(tr + r) * Cc + tc + tx;
        u16 v;
        if (fp32) v = f2b(((const float*)src)[e]);
        else      v = ((const u16*)src)[e];
        t[r][tx] = v;
    }
    __syncthreads();
#pragma unroll
    for (int i = 0; i < 4; ++i) {
        const int r = ty + i * 8;
        dst[(size_t)(tc + r) * R + tr + tx] = t[tx][r];
    }
}

// ---------------------------------------------------------------------------
// XCD-aware block remap: linear id lin -> XCD = lin&7 (HW round-robin), give
// each XCD a contiguous 16-m-tile strip x all 8 n-tiles so A-tiles and weight
// strips stay in one XCD's (non-coherent) L2. Perf heuristic only.
// ---------------------------------------------------------------------------
__device__ __forceinline__ void tile_swizzle(int& m0, int& n0) {
    const int lin = blockIdx.y * gridDim.x + blockIdx.x;  // 0..1023
    const int xcd = lin & 7;
    const int loc = lin >> 3;                             // 0..127
    m0 = (xcd * 16 + (loc & 15)) * 128;
    n0 = (loc >> 4) * 128;
}

// ---------------------------------------------------------------------------
// 128x128-tile bf16 MFMA GEMM, BK=64, global_load_lds width-16 staging with
// XOR bank swizzle, bias epilogue.
// A: [M,K] row-major bf16.  BT: [N,K] row-major (B transposed). C = A@B + bias.
// LDS layout: row stride 64 u16 (128 B); 16B chunk (row, kc) stored at column
// slot kc ^ (row & 7). Staging keeps DMA constraint (dest = base + lane*16B):
// lane i covers (row = c*8 + (i>>3), global kc = (i&7) ^ (i>>3)).
// ---------------------------------------------------------------------------
__global__ __launch_bounds__(256, 2) void gemm128(
    const u16* __restrict__ A, const u16* __restrict__ BT,
    const u16* __restrict__ bias, u16* __restrict__ C,
    int M, int N, int K)
{
    __align__(16) __shared__ u16 As[128 * 64];
    __align__(16) __shared__ u16 Bs[128 * 64];

    const int tid  = threadIdx.x;
    const int lane = tid & 63;
    const int wid  = tid >> 6;
    const int wr   = wid >> 1;
    const int wc   = wid & 1;

    int m0, n0;
    tile_swizzle(m0, n0);

    floatx4 acc[4][4] = {};

    // staging coords (per chunk of 8 rows x 64 cols = 1 KB)
    const int srow = lane >> 3;                       // 0..7
    const int scol = 8 * ((lane & 7) ^ (lane >> 3));  // XOR swizzle source col
    const int cb   = wid * 4;                         // 4 chunks per wave per tile
    const u16* Ag[4]; const u16* Bg[4];
    u16 *Al[4], *Bl[4];
#pragma unroll
    for (int j = 0; j < 4; ++j) {
        const int c = cb + j;
        const int r = c * 8 + srow;
        Ag[j] = A  + (size_t)(m0 + r) * K + scol;
        Bg[j] = BT + (size_t)(n0 + r) * K + scol;
        Al[j] = As + c * 512;
        Bl[j] = Bs + c * 512;
    }

    const int quad = lane >> 4;
    const int l16  = lane & 15;
    const int swz  = l16 & 7;

    const int nk = K >> 6;
    for (int kt = 0; kt < nk; ++kt) {
        __syncthreads();                 // previous iter's LDS reads done
#pragma unroll
        for (int j = 0; j < 4; ++j) {
            gld16(Ag[j], Al[j]);  gld16(Bg[j], Bl[j]);
            Ag[j] += 64; Bg[j] += 64;
        }
        __syncthreads();                 // drains DMA before compute

#pragma unroll
        for (int kk = 0; kk < 2; ++kk) {
            const int slot = ((kk * 4 + quad) ^ swz) * 8;
            bf16x8 af[4], bfr[4];
#pragma unroll
            for (int i = 0; i < 4; ++i) {
                af[i]  = *(const bf16x8*)(As + (wr * 64 + i * 16 + l16) * 64 + slot);
                bfr[i] = *(const bf16x8*)(Bs + (wc * 64 + i * 16 + l16) * 64 + slot);
            }
#pragma unroll
            for (int i = 0; i < 4; ++i)
#pragma unroll
                for (int j = 0; j < 4; ++j)
                    acc[i][j] = __builtin_amdgcn_mfma_f32_16x16x32_bf16(af[i], bfr[j], acc[i][j], 0, 0, 0);
        }
    }

#pragma unroll
    for (int i = 0; i < 4; ++i) {
        const int rowb = m0 + wr * 64 + i * 16 + quad * 4;
#pragma unroll
        for (int j = 0; j < 4; ++j) {
            const int col = n0 + wc * 64 + j * 16 + l16;
            const float bv = b2f(bias[col]);
#pragma unroll
            for (int r = 0; r < 4; ++r)
                C[(size_t)(rowb + r) * N + col] = f2b(acc[i][j][r] + bv);
        }
    }
}

// ---------------------------------------------------------------------------
// Fused highway GEMM: dual accumulators (t-gate, h-layer share A tile);
// epilogue h_new = h_old + sig(t)*(tanh(h)-h_old), h_old re-read from A.
// BK=64, XOR-swizzled LDS, XCD-aware tiles, 48 KB LDS.
// ---------------------------------------------------------------------------
__global__ __launch_bounds__(256, 2) void gemm_hw(
    const u16* __restrict__ A,      // [M,K] = h
    const u16* __restrict__ WtT,    // [N,K]
    const u16* __restrict__ WhT,    // [N,K]
    const u16* __restrict__ bt, const u16* __restrict__ bh,
    u16* __restrict__ Hout,
    int M, int N, int K)
{
    __align__(16) __shared__ u16 As [128 * 64];
    __align__(16) __shared__ u16 Bts[128 * 64];
    __align__(16) __shared__ u16 Bhs[128 * 64];

    const int tid  = threadIdx.x;
    const int lane = tid & 63;
    const int wid  = tid >> 6;
    const int wr   = wid >> 1;
    const int wc   = wid & 1;

    int m0, n0;
    tile_swizzle(m0, n0);

    floatx4 acct[4][4] = {};
    floatx4 acch[4][4] = {};

    const int srow = lane >> 3;
    const int scol = 8 * ((lane & 7) ^ (lane >> 3));
    const int cb   = wid * 4;
    const u16* Ag[4]; const u16* Tg[4]; const u16* Hg[4];
    u16 *Al[4], *Tl[4], *Hl[4];
#pragma unroll
    for (int j = 0; j < 4; ++j) {
        const int c = cb + j;
        const int r = c * 8 + srow;
        Ag[j] = A   + (size_t)(m0 + r) * K + scol;
        Tg[j] = WtT + (size_t)(n0 + r) * K + scol;
        Hg[j] = WhT + (size_t)(n0 + r) * K + scol;
        Al[j] = As  + c * 512;
        Tl[j] = Bts + c * 512;
        Hl[j] = Bhs + c * 512;
    }

    const int quad = lane >> 4;
    const int l16  = lane & 15;
    const int swz  = l16 & 7;

    const int nk = K >> 6;
    for (int kt = 0; kt < nk; ++kt) {
        __syncthreads();
#pragma unroll
        for (int j = 0; j < 4; ++j) {
            gld16(Ag[j], Al[j]);  gld16(Tg[j], Tl[j]);  gld16(Hg[j], Hl[j]);
            Ag[j] += 64; Tg[j] += 64; Hg[j] += 64;
        }
        __syncthreads();

#pragma unroll
        for (int kk = 0; kk < 2; ++kk) {
            const int slot = ((kk * 4 + quad) ^ swz) * 8;
            bf16x8 af[4], btf[4], bhf[4];
#pragma unroll
            for (int i = 0; i < 4; ++i) {
                af[i]  = *(const bf16x8*)(As  + (wr * 64 + i * 16 + l16) * 64 + slot);
                btf[i] = *(const bf16x8*)(Bts + (wc * 64 + i * 16 + l16) * 64 + slot);
                bhf[i] = *(const bf16x8*)(Bhs + (wc * 64 + i * 16 + l16) * 64 + slot);
            }
#pragma unroll
            for (int i = 0; i < 4; ++i)
#pragma unroll
                for (int j = 0; j < 4; ++j) {
                    acct[i][j] = __builtin_amdgcn_mfma_f32_16x16x32_bf16(af[i], btf[j], acct[i][j], 0, 0, 0);
                    acch[i][j] = __builtin_amdgcn_mfma_f32_16x16x32_bf16(af[i], bhf[j], acch[i][j], 0, 0, 0);
                }
        }
    }

#pragma unroll
    for (int i = 0; i < 4; ++i) {
        const int rowb = m0 + wr * 64 + i * 16 + quad * 4;
#pragma unroll
        for (int j = 0; j < 4; ++j) {
            const int col = n0 + wc * 64 + j * 16 + l16;
            const float btv = b2f(bt[col]);
            const float bhv = b2f(bh[col]);
#pragma unroll
            for (int r = 0; r < 4; ++r) {
                const size_t idx = (size_t)(rowb + r) * N + col;
                const float hold = b2f(A[idx]);
                const float tg = sigm(acct[i][j][r] + btv);
                const float hl = tanh_f(acch[i][j][r] + bhv);
                Hout[idx] = f2b(hold + tg * (hl - hold));
            }
        }
    }
}

// ---------------------------------------------------------------------------
// in-place cumsum over t (fp32 accumulate): g is [B=64, T=256, H=1024] bf16
// ---------------------------------------------------------------------------
__global__ void cumsum_t(u16* g) {
    const int id = blockIdx.x * 256 + threadIdx.x;  // 65536 = B*H
    const int b = id >> 10, f = id & 1023;
    size_t base = (size_t)b * SEQ * HID + f;
    float acc = 0.f;
#pragma unroll 4
    for (int t = 0; t < SEQ; ++t) {
        size_t idx = base + (size_t)t * HID;
        acc += b2f(g[idx]);
        g[idx] = f2b(acc);
    }
}

// sum over t -> fp32 [B, H]
__global__ void sum_t(const u16* __restrict__ g, float* __restrict__ out) {
    const int id = blockIdx.x * 256 + threadIdx.x;  // 65536
    const int b = id >> 10, f = id & 1023;
    size_t base = (size_t)b * SEQ * HID + f;
    float acc = 0.f;
#pragma unroll 4
    for (int t = 0; t < SEQ; ++t)
        acc += b2f(g[base + (size_t)t * HID]);
    out[id] = acc;
}

// final fc, dtype-branched on both W/bias reads and the output write
__global__ void fc_final(const float* __restrict__ hf, const void* __restrict__ W,
                         const void* __restrict__ bias, void* __restrict__ out,
                         const int* __restrict__ flag) {
    __shared__ float sh[HID];
    const int fp32 = *flag;
    const int b = blockIdx.x, o = threadIdx.x;      // 64 blocks x 128 threads
    for (int k = o; k < HID; k += 128) sh[k] = hf[(size_t)b * HID + k];
    __syncthreads();
    float acc;
    if (fp32) {
        acc = ((const float*)bias)[o];
        for (int k = 0; k < HID; ++k)
            acc += sh[k] * ((const float*)W)[(size_t)k * OUTDIM + o];
        ((float*)out)[b * OUTDIM + o] = acc;
    } else {
        acc = b2f(((const u16*)bias)[o]);
        for (int k = 0; k < HID; ++k)
            acc += sh[k] * b2f(((const u16*)W)[(size_t)k * OUTDIM + o]);
        ((u16*)out)[b * OUTDIM + o] = f2b(acc);
    }
}

// ---------------------------------------------------------------------------
extern "C" void kernel_launch(void* const* d_in, const int* in_sizes, int n_in,
                              void* d_out, int out_size, void* d_ws, size_t ws_size,
                              hipStream_t stream) {
    const void* x      = d_in[0];
    const void* l0_Win = d_in[1];
    const void* l0_bin = d_in[2];
    const void* l0_Wh  = d_in[3];
    const void* l0_bh  = d_in[4];
    const void* l0_Wt  = d_in[5];
    const void* l0_bt  = d_in[6];
    const void* l1_Win = d_in[7];
    const void* l1_bin = d_in[8];
    const void* l1_Wh  = d_in[9];
    const void* l1_bh  = d_in[10];
    const void* l1_Wt  = d_in[11];
    const void* l1_bt  = d_in[12];
    const void* fc_W   = d_in[13];
    const void* fc_b   = d_in[14];

    char* ws = (char*)d_ws;
    u16* Pa = (u16*)(ws);                       // 32 MB; hfinal reuses its base at the tail
    u16* Pb = (u16*)(ws + 33554432);            // 32 MB; x-clean occupies its first 4 MB
    u16* xc = Pb;                               // [16384,128] clean bf16 x
    u16* tW = (u16*)(ws + 67108864);
    u16* tWin0 = tW;                  // [1024,128]
    u16* tWt00 = tWin0 + 131072;      // each [1024,1024]
    u16* tWt01 = tWt00 + 1048576;
    u16* tWh00 = tWt01 + 1048576;
    u16* tWh01 = tWh00 + 1048576;
    u16* tWin1 = tWh01 + 1048576;
    u16* tWt10 = tWin1 + 1048576;
    u16* tWt11 = tWt10 + 1048576;
    u16* tWh10 = tWt11 + 1048576;
    u16* tWh11 = tWh10 + 1048576;
    u16* smallb = tWh11 + 1048576;    // bias copies: 10240 elems
    u16* binc0 = smallb;              // 1024
    u16* bhc0  = binc0 + 1024;        // 2048 (both depths)
    u16* btc0  = bhc0 + 2048;         // 2048
    u16* binc1 = btc0 + 2048;         // 1024
    u16* bhc1  = binc1 + 1024;        // 2048
    u16* btc1  = bhc1 + 2048;         // 2048
    int* flag  = (int*)(btc1 + 2048);
    float* hfinal = (float*)Pa;       // [64,1024] fp32, Pa free by then

    detect_dtype<<<1, 256, 0, stream>>>((const u16*)l0_Wh, flag);

    const long DD = (long)HID * HID;   // element offset of depth-1 slice
    TListO L;
    L.s[0] = l0_Win; L.d[0] = tWin0; L.R[0] = INDIM; L.Cc[0] = HID; L.off[0] = 0;
    L.s[1] = l0_Wt;  L.d[1] = tWt00; L.R[1] = HID;   L.Cc[1] = HID; L.off[1] = 0;
    L.s[2] = l0_Wt;  L.d[2] = tWt01; L.R[2] = HID;   L.Cc[2] = HID; L.off[2] = DD;
    L.s[3] = l0_Wh;  L.d[3] = tWh00; L.R[3] = HID;   L.Cc[3] = HID; L.off[3] = 0;
    L.s[4] = l0_Wh;  L.d[4] = tWh01; L.R[4] = HID;   L.Cc[4] = HID; L.off[4] = DD;
    L.s[5] = l1_Win; L.d[5] = tWin1; L.R[5] = HID;   L.Cc[5] = HID; L.off[5] = 0;
    L.s[6] = l1_Wt;  L.d[6] = tWt10; L.R[6] = HID;   L.Cc[6] = HID; L.off[6] = 0;
    L.s[7] = l1_Wt;  L.d[7] = tWt11; L.R[7] = HID;   L.Cc[7] = HID; L.off[7] = DD;
    L.s[8] = l1_Wh;  L.d[8] = tWh10; L.R[8] = HID;   L.Cc[8] = HID; L.off[8] = 0;
    L.s[9] = l1_Wh;  L.d[9] = tWh11; L.R[9] = HID;   L.Cc[9] = HID; L.off[9] = DD;
    transpose10<<<dim3(32, 32, 10), dim3(32, 8), 0, stream>>>(L, flag);

    CvtList C7;
    C7.s[0] = x;      C7.d[0] = xc;    C7.n[0] = MROWS * INDIM;
    C7.s[1] = l0_bin; C7.d[1] = binc0; C7.n[1] = HID;
    C7.s[2] = l0_bh;  C7.d[2] = bhc0;  C7.n[2] = 2 * HID;
    C7.s[3] = l0_bt;  C7.d[3] = btc0;  C7.n[3] = 2 * HID;
    C7.s[4] = l1_bin; C7.d[4] = binc1; C7.n[4] = HID;
    C7.s[5] = l1_bh;  C7.d[5] = bhc1;  C7.n[5] = 2 * HID;
    C7.s[6] = l1_bt;  C7.d[6] = btc1;  C7.n[6] = 2 * HID;
    convert7<<<dim3(512, 7), 256, 0, stream>>>(C7, flag);

    // ---- layer 0 ----
    gemm128<<<dim3(8, 128), 256, 0, stream>>>(xc, tWin0, binc0, Pa, MROWS, HID, INDIM);
    gemm_hw<<<dim3(8, 128), 256, 0, stream>>>(Pa, tWt00, tWh00, btc0, bhc0, Pb, MROWS, HID, HID);
    gemm_hw<<<dim3(8, 128), 256, 0, stream>>>(Pb, tWt01, tWh01, btc0 + HID, bhc0 + HID, Pa, MROWS, HID, HID);
    cumsum_t<<<256, 256, 0, stream>>>(Pa);      // Pa = y0

    // ---- layer 1 ----
    gemm128<<<dim3(8, 128), 256, 0, stream>>>(Pa, tWin1, binc1, Pb, MROWS, HID, HID);
    gemm_hw<<<dim3(8, 128), 256, 0, stream>>>(Pb, tWt10, tWh10, btc1, bhc1, Pa, MROWS, HID, HID);
    gemm_hw<<<dim3(8, 128), 256, 0, stream>>>(Pa, tWt11, tWh11, btc1 + HID, bhc1 + HID, Pb, MROWS, HID, HID);

    // ---- tail ----
    sum_t<<<256, 256, 0, stream>>>(Pb, hfinal);
    fc_final<<<64, 128, 0, stream>>>(hfinal, fc_W, fc_b, d_out, flag);
}